// Round 1
// baseline (906.398 us; speedup 1.0000x reference)
//
#include <hip/hip_runtime.h>
#include <hip/hip_bf16.h>

typedef __attribute__((ext_vector_type(8))) short short8;
typedef __attribute__((ext_vector_type(4))) float f32x4;

// fp32 -> bf16 RNE
static __device__ __forceinline__ unsigned short f2bf(float f) {
    unsigned int x = __float_as_uint(f);
    x += 0x7fffu + ((x >> 16) & 1u);
    return (unsigned short)(x >> 16);
}
static __device__ __forceinline__ float bf2f(unsigned short u) {
    return __uint_as_float(((unsigned int)u) << 16);
}

// ---------------------------------------------------------------- converts
__global__ __launch_bounds__(256) void cvt_x_kernel(const float* __restrict__ in,
                                                    unsigned short* __restrict__ outb,
                                                    int n4) {
    int i = blockIdx.x * 256 + threadIdx.x;
    if (i < n4) {
        f32x4 v = *(const f32x4*)(in + (size_t)i * 4);
        ushort4 o;
        o.x = f2bf(v[0]); o.y = f2bf(v[1]); o.z = f2bf(v[2]); o.w = f2bf(v[3]);
        *(ushort4*)(outb + (size_t)i * 4) = o;
    }
}

// W [1024 x 3072] fp32  ->  WT [3072 x 1024] bf16   (tiled LDS transpose)
__global__ __launch_bounds__(256) void cvt_wt_kernel(const float* __restrict__ W,
                                                     unsigned short* __restrict__ WT) {
    __shared__ float t[64][65];
    const int n0 = blockIdx.x * 64;   // 48
    const int k0 = blockIdx.y * 64;   // 16
    const int tid = threadIdx.x;
#pragma unroll
    for (int i = 0; i < 16; ++i) {
        int lin = tid + i * 256;
        int rr = lin >> 6, cc = lin & 63;
        t[rr][cc] = W[(size_t)(k0 + rr) * 3072 + n0 + cc];
    }
    __syncthreads();
#pragma unroll
    for (int i = 0; i < 16; ++i) {
        int lin = tid + i * 256;
        int nn = lin >> 6, kk = lin & 63;
        WT[(size_t)(n0 + nn) * 1024 + k0 + kk] = f2bf(t[kk][nn]);
    }
}

// ---------------------------------------------------------------- GEMM
// C[4096,3072] = A[4096,1024] @ W[1024,3072], both operands given as [rows,K] bf16.
// Epilogue scatters into k/q (bf16 [B,H,S,64]) and vT (bf16 [B,H,64,S]).
__global__ __launch_bounds__(256) void gemm_kqv_kernel(
    const unsigned short* __restrict__ A,   // xb  [4096,1024]
    const unsigned short* __restrict__ BT,  // WTb [3072,1024]
    unsigned short* __restrict__ qb,
    unsigned short* __restrict__ kb,
    unsigned short* __restrict__ vtb) {
    __shared__ unsigned short As[128][72];
    __shared__ unsigned short Bs[128][72];
    const int tid = threadIdx.x;
    const int w = tid >> 6, lane = tid & 63;
    const int quad = lane >> 4, cl = lane & 15;
    const int m0 = blockIdx.y * 128, n0 = blockIdx.x * 128;
    const int wm = (w >> 1) * 64, wn = (w & 1) * 64;

    f32x4 acc[4][4] = {};

    for (int kk = 0; kk < 1024; kk += 64) {
#pragma unroll
        for (int i = 0; i < 4; ++i) {
            int c = tid + i * 256;                 // 0..1023 chunk id
            int row = c >> 3, c8 = (c & 7) * 8;    // 8 chunks of 8 bf16 per row
            *(uint4*)&As[row][c8] = *(const uint4*)(A + (size_t)(m0 + row) * 1024 + kk + c8);
            *(uint4*)&Bs[row][c8] = *(const uint4*)(BT + (size_t)(n0 + row) * 1024 + kk + c8);
        }
        __syncthreads();
#pragma unroll
        for (int kc = 0; kc < 2; ++kc) {
            short8 af[4], bfr[4];
#pragma unroll
            for (int i = 0; i < 4; ++i) {
                af[i] = *(const short8*)&As[wm + i * 16 + cl][kc * 32 + quad * 8];
                bfr[i] = *(const short8*)&Bs[wn + i * 16 + cl][kc * 32 + quad * 8];
            }
#pragma unroll
            for (int im = 0; im < 4; ++im)
#pragma unroll
                for (int in = 0; in < 4; ++in)
                    acc[im][in] = __builtin_amdgcn_mfma_f32_16x16x32_bf16(
                        af[im], bfr[in], acc[im][in], 0, 0, 0);
        }
        __syncthreads();
    }

    // epilogue: chunk order is k, q, v (jnp.split order)
#pragma unroll
    for (int im = 0; im < 4; ++im) {
#pragma unroll
        for (int in = 0; in < 4; ++in) {
#pragma unroll
            for (int rg = 0; rg < 4; ++rg) {
                int gm = m0 + wm + im * 16 + quad * 4 + rg;   // row in [0,4096)
                int gn = n0 + wn + in * 16 + cl;              // col in [0,3072)
                unsigned short bv = f2bf(acc[im][in][rg]);
                int b = gm >> 11, s = gm & 2047;
                int chunk = gn >> 10, d = gn & 1023;
                int hh = d >> 6, dd = d & 63;
                size_t bh = (size_t)(b * 16 + hh);
                if (chunk == 0)
                    kb[(bh * 2048 + s) * 64 + dd] = bv;
                else if (chunk == 1)
                    qb[(bh * 2048 + s) * 64 + dd] = bv;
                else
                    vtb[(bh * 64 + dd) * 2048 + s] = bv;
            }
        }
    }
}

// ---------------------------------------------------------------- fused attention
// grid: (qt=32, h=16, b=2); block 256 = 4 waves x 16 q-rows each.
__global__ __launch_bounds__(256) void attn_kernel(
    const unsigned short* __restrict__ qb,   // [B,H,S,64]
    const unsigned short* __restrict__ kb,   // [B,H,S,64]
    const unsigned short* __restrict__ vtb,  // [B,H,64,S]
    float* __restrict__ out_,                // [B,S,1024]
    float* __restrict__ attn) {              // [B,H,S,S]
    const int qt = blockIdx.x;
    const int h = blockIdx.y;
    const int b = blockIdx.z;
    const int bh = b * 16 + h;
    const int tid = threadIdx.x;
    const int w = tid >> 6;
    const int lane = tid & 63;
    const int quad = lane >> 4;
    const int cl = lane & 15;
    const int q0 = qt * 64;
    const int row0 = q0 + w * 16;

    const unsigned short* Qh = qb + (size_t)bh * 2048 * 64;
    const unsigned short* Kh = kb + (size_t)bh * 2048 * 64;
    const unsigned short* Vh = vtb + (size_t)bh * 64 * 2048;
    float* attnh = attn + (size_t)bh * 2048 * 2048;

    // Q fragments (A-operand): lane holds Q[row0+cl][kc*32 + quad*8 + j]
    short8 aq0 = *(const short8*)(Qh + (size_t)(row0 + cl) * 64 + quad * 8);
    short8 aq1 = *(const short8*)(Qh + (size_t)(row0 + cl) * 64 + 32 + quad * 8);

    const float mh = exp2f(-0.5f * (float)(h + 1));  // ALiBi slope 2^-((h+1)/2)
    const float sc1 = 1.0f / 32.0f;                  // 1/sqrt(1024)

    // ---- trip 1: row sums of exp(score) (max-free softmax: scores are O(1))
    float rsum[4] = {0.f, 0.f, 0.f, 0.f};
    for (int jt = 0; jt <= qt; ++jt) {
        const int j0 = jt * 64;
#pragma unroll
        for (int nt = 0; nt < 4; ++nt) {
            const unsigned short* Kp = Kh + (size_t)(j0 + nt * 16 + cl) * 64 + quad * 8;
            short8 bk0 = *(const short8*)(Kp);
            short8 bk1 = *(const short8*)(Kp + 32);
            f32x4 s = {0.f, 0.f, 0.f, 0.f};
            s = __builtin_amdgcn_mfma_f32_16x16x32_bf16(aq0, bk0, s, 0, 0, 0);
            s = __builtin_amdgcn_mfma_f32_16x16x32_bf16(aq1, bk1, s, 0, 0, 0);
            const int jc = j0 + nt * 16 + cl;
#pragma unroll
            for (int rg = 0; rg < 4; ++rg) {
                int irow = row0 + quad * 4 + rg;
                float p = (jc <= irow)
                              ? __expf(s[rg] * sc1 + mh * (float)(jc - irow))
                              : 0.f;
                rsum[rg] += p;
            }
        }
    }
#pragma unroll
    for (int rg = 0; rg < 4; ++rg) {
        float v = rsum[rg];
        v += __shfl_xor(v, 1);
        v += __shfl_xor(v, 2);
        v += __shfl_xor(v, 4);
        v += __shfl_xor(v, 8);
        rsum[rg] = 1.0f / v;   // now inv row-sum, valid on every lane of the quad
    }

    // ---- trip 2: recompute, normalize, emit attn, accumulate O = P @ V
    __shared__ unsigned short Ps[4][16][72];  // per-wave P strip, C-layout -> A-layout
    f32x4 oacc[4] = {};
    for (int jt = 0; jt <= qt; ++jt) {
        const int j0 = jt * 64;
#pragma unroll
        for (int nt = 0; nt < 4; ++nt) {
            const unsigned short* Kp = Kh + (size_t)(j0 + nt * 16 + cl) * 64 + quad * 8;
            short8 bk0 = *(const short8*)(Kp);
            short8 bk1 = *(const short8*)(Kp + 32);
            f32x4 s = {0.f, 0.f, 0.f, 0.f};
            s = __builtin_amdgcn_mfma_f32_16x16x32_bf16(aq0, bk0, s, 0, 0, 0);
            s = __builtin_amdgcn_mfma_f32_16x16x32_bf16(aq1, bk1, s, 0, 0, 0);
            const int jc = j0 + nt * 16 + cl;
#pragma unroll
            for (int rg = 0; rg < 4; ++rg) {
                int irow = row0 + quad * 4 + rg;
                float p = (jc <= irow)
                              ? __expf(s[rg] * sc1 + mh * (float)(jc - irow)) * rsum[rg]
                              : 0.f;
                Ps[w][quad * 4 + rg][nt * 16 + cl] = f2bf(p);
            }
        }
        // P strip: A-operand fragments (lane = row cl, k contiguous)
        short8 pa0 = *(const short8*)&Ps[w][cl][quad * 8];
        short8 pa1 = *(const short8*)&Ps[w][cl][32 + quad * 8];

        // attn write: row row0+cl, cols j0+quad*8..+8 and j0+32+quad*8..+8
        {
            float* arow = attnh + (size_t)(row0 + cl) * 2048 + j0;
            f32x4 v0, v1, v2, v3;
#pragma unroll
            for (int j = 0; j < 4; ++j) {
                v0[j] = bf2f((unsigned short)pa0[j]);
                v1[j] = bf2f((unsigned short)pa0[j + 4]);
                v2[j] = bf2f((unsigned short)pa1[j]);
                v3[j] = bf2f((unsigned short)pa1[j + 4]);
            }
            *(f32x4*)(arow + quad * 8) = v0;
            *(f32x4*)(arow + quad * 8 + 4) = v1;
            *(f32x4*)(arow + 32 + quad * 8) = v2;
            *(f32x4*)(arow + 32 + quad * 8 + 4) = v3;
        }

        // O += P @ V   (B-operand: vT[n][k] contiguous in k)
#pragma unroll
        for (int on = 0; on < 4; ++on) {
            const unsigned short* Vp = Vh + (size_t)(on * 16 + cl) * 2048 + j0 + quad * 8;
            short8 bv0 = *(const short8*)(Vp);
            short8 bv1 = *(const short8*)(Vp + 32);
            oacc[on] = __builtin_amdgcn_mfma_f32_16x16x32_bf16(pa0, bv0, oacc[on], 0, 0, 0);
            oacc[on] = __builtin_amdgcn_mfma_f32_16x16x32_bf16(pa1, bv1, oacc[on], 0, 0, 0);
        }
    }

    // O epilogue: out[b, s, h*64 + d]
#pragma unroll
    for (int on = 0; on < 4; ++on) {
#pragma unroll
        for (int rg = 0; rg < 4; ++rg) {
            int srow = row0 + quad * 4 + rg;
            out_[((size_t)b * 2048 + srow) * 1024 + h * 64 + on * 16 + cl] = oacc[on][rg];
        }
    }

    // zero-fill strictly-future columns (d_out is poisoned, zeros must be written)
    const int jz = (qt + 1) * 64;
    if (jz < 2048) {
        f32x4 z = {0.f, 0.f, 0.f, 0.f};
        for (int rr = 0; rr < 16; ++rr) {
            float* dst = attnh + (size_t)(row0 + rr) * 2048;
            for (int c = jz + lane * 4; c < 2048; c += 256)
                *(f32x4*)(dst + c) = z;
        }
    }
}

// ---------------------------------------------------------------- launch
extern "C" void kernel_launch(void* const* d_in, const int* in_sizes, int n_in,
                              void* d_out, int out_size, void* d_ws, size_t ws_size,
                              hipStream_t stream) {
    const float* x = (const float*)d_in[0];     // [2,2048,1024]
    const float* Wk = (const float*)d_in[1];    // [1024,3072]
    float* out = (float*)d_out;                 // [2,2048,1024] fp32
    float* attn = out + (size_t)2 * 2048 * 1024;  // [2,16,2048,2048] fp32

    unsigned short* xb = (unsigned short*)d_ws;                 // 8 MB
    unsigned short* wtb = xb + (size_t)4096 * 1024;             // 6 MB
    unsigned short* qb = wtb + (size_t)3072 * 1024;             // 8 MB
    unsigned short* kb = qb + (size_t)32 * 2048 * 64;           // 8 MB
    unsigned short* vtb = kb + (size_t)32 * 2048 * 64;          // 8 MB

    cvt_x_kernel<<<dim3(4096), dim3(256), 0, stream>>>(x, xb, 4096 * 1024 / 4);
    cvt_wt_kernel<<<dim3(48, 16), dim3(256), 0, stream>>>(Wk, wtb);
    gemm_kqv_kernel<<<dim3(24, 32), dim3(256), 0, stream>>>(xb, wtb, qb, kb, vtb);
    attn_kernel<<<dim3(32, 16, 2), dim3(256), 0, stream>>>(qb, kb, vtb, out, attn);
}

// Round 2
// 873.656 us; speedup vs baseline: 1.0375x; 1.0375x over previous
//
#include <hip/hip_runtime.h>
#include <hip/hip_bf16.h>

typedef __attribute__((ext_vector_type(8))) short short8;
typedef __attribute__((ext_vector_type(4))) float f32x4;

// fp32 -> bf16 RNE
static __device__ __forceinline__ unsigned short f2bf(float f) {
    unsigned int x = __float_as_uint(f);
    x += 0x7fffu + ((x >> 16) & 1u);
    return (unsigned short)(x >> 16);
}
static __device__ __forceinline__ float bf2f(unsigned short u) {
    return __uint_as_float(((unsigned int)u) << 16);
}

// ---------------------------------------------------------------- converts
__global__ __launch_bounds__(256) void cvt_x_kernel(const float* __restrict__ in,
                                                    unsigned short* __restrict__ outb,
                                                    int n4) {
    int i = blockIdx.x * 256 + threadIdx.x;
    if (i < n4) {
        f32x4 v = *(const f32x4*)(in + (size_t)i * 4);
        ushort4 o;
        o.x = f2bf(v[0]); o.y = f2bf(v[1]); o.z = f2bf(v[2]); o.w = f2bf(v[3]);
        *(ushort4*)(outb + (size_t)i * 4) = o;
    }
}

// W [1024 x 3072] fp32  ->  WT [3072 x 1024] bf16   (tiled LDS transpose)
__global__ __launch_bounds__(256) void cvt_wt_kernel(const float* __restrict__ W,
                                                     unsigned short* __restrict__ WT) {
    __shared__ float t[64][65];
    const int n0 = blockIdx.x * 64;   // 48
    const int k0 = blockIdx.y * 64;   // 16
    const int tid = threadIdx.x;
#pragma unroll
    for (int i = 0; i < 16; ++i) {
        int lin = tid + i * 256;
        int rr = lin >> 6, cc = lin & 63;
        t[rr][cc] = W[(size_t)(k0 + rr) * 3072 + n0 + cc];
    }
    __syncthreads();
#pragma unroll
    for (int i = 0; i < 16; ++i) {
        int lin = tid + i * 256;
        int nn = lin >> 6, kk = lin & 63;
        WT[(size_t)(n0 + nn) * 1024 + k0 + kk] = f2bf(t[kk][nn]);
    }
}

// ---------------------------------------------------------------- GEMM
// C[4096,3072] = A[4096,1024] @ W[1024,3072], operands [rows,K] bf16.
// Epilogue: stage C tile in LDS (reusing As/Bs), then COALESCED 16B stores to
// k/q ([B,H,S,64]) or vT ([B,H,64,S]; tile staged transposed in LDS).
__global__ __launch_bounds__(256) void gemm_kqv_kernel(
    const unsigned short* __restrict__ A,   // xb  [4096,1024]
    const unsigned short* __restrict__ BT,  // WTb [3072,1024]
    unsigned short* __restrict__ qb,
    unsigned short* __restrict__ kb,
    unsigned short* __restrict__ vtb) {
    __shared__ unsigned short smem[2 * 128 * 72];           // 36864 B
    unsigned short (*As)[72] = (unsigned short(*)[72])smem;
    unsigned short (*Bs)[72] = (unsigned short(*)[72])(smem + 128 * 72);
    const int tid = threadIdx.x;
    const int w = tid >> 6, lane = tid & 63;
    const int quad = lane >> 4, cl = lane & 15;
    const int m0 = blockIdx.y * 128, n0 = blockIdx.x * 128;
    const int wm = (w >> 1) * 64, wn = (w & 1) * 64;

    f32x4 acc[4][4] = {};

    for (int kk = 0; kk < 1024; kk += 64) {
#pragma unroll
        for (int i = 0; i < 4; ++i) {
            int c = tid + i * 256;                 // 0..1023 chunk id
            int row = c >> 3, c8 = (c & 7) * 8;    // 8 chunks of 8 bf16 per row
            *(uint4*)&As[row][c8] = *(const uint4*)(A + (size_t)(m0 + row) * 1024 + kk + c8);
            *(uint4*)&Bs[row][c8] = *(const uint4*)(BT + (size_t)(n0 + row) * 1024 + kk + c8);
        }
        __syncthreads();
#pragma unroll
        for (int kc = 0; kc < 2; ++kc) {
            short8 af[4], bfr[4];
#pragma unroll
            for (int i = 0; i < 4; ++i) {
                af[i] = *(const short8*)&As[wm + i * 16 + cl][kc * 32 + quad * 8];
                bfr[i] = *(const short8*)&Bs[wn + i * 16 + cl][kc * 32 + quad * 8];
            }
#pragma unroll
            for (int im = 0; im < 4; ++im)
#pragma unroll
                for (int in = 0; in < 4; ++in)
                    acc[im][in] = __builtin_amdgcn_mfma_f32_16x16x32_bf16(
                        af[im], bfr[in], acc[im][in], 0, 0, 0);
        }
        __syncthreads();
    }
    // k-loop ended with __syncthreads(): safe to reuse smem as C-tile staging.
    unsigned short (*Cs)[130] = (unsigned short(*)[130])smem;  // 33280 B <= 36864 B

    const int chunk = n0 >> 10;           // 0:k 1:q 2:v (jnp.split order)
    const int d0 = n0 & 1023;
    const int b = m0 >> 11;               // tile never crosses batch boundary
    const int s_base = m0 & 2047;

    if (chunk == 2) {
        // stage TRANSPOSED: Cs[d-idx][s-idx]
#pragma unroll
        for (int im = 0; im < 4; ++im)
#pragma unroll
            for (int in = 0; in < 4; ++in)
#pragma unroll
                for (int rg = 0; rg < 4; ++rg)
                    Cs[wn + in * 16 + cl][wm + im * 16 + quad * 4 + rg] =
                        f2bf(acc[im][in][rg]);
        __syncthreads();
#pragma unroll
        for (int it = 0; it < 8; ++it) {
            int l = it * 2048 + tid * 8;
            int c = l >> 7;               // d-index 0..127
            int r = l & 127;              // s-offset (multiple of 8)
            int d = d0 + c, hh = d >> 6, dd = d & 63;
            size_t dst = ((size_t)(b * 16 + hh) * 64 + dd) * 2048 + s_base + r;
            *(uint4*)(vtb + dst) = *(const uint4*)&Cs[c][r];
        }
    } else {
#pragma unroll
        for (int im = 0; im < 4; ++im)
#pragma unroll
            for (int in = 0; in < 4; ++in)
#pragma unroll
                for (int rg = 0; rg < 4; ++rg)
                    Cs[wm + im * 16 + quad * 4 + rg][wn + in * 16 + cl] =
                        f2bf(acc[im][in][rg]);
        __syncthreads();
        unsigned short* outp = (chunk == 0) ? kb : qb;
#pragma unroll
        for (int it = 0; it < 8; ++it) {
            int l = it * 2048 + tid * 8;
            int r = l >> 7;               // s-offset
            int c = l & 127;              // d-index (multiple of 8)
            int d = d0 + c, hh = d >> 6, dd = d & 63;
            size_t dst = ((size_t)(b * 16 + hh) * 2048 + s_base + r) * 64 + dd;
            *(uint4*)(outp + dst) = *(const uint4*)&Cs[r][c];
        }
    }
}

// ---------------------------------------------------------------- fused attention
// grid: (qt=32, h=16, b=2); block 256 = 4 waves x 16 q-rows each.
// LPT: heavy q-tiles dispatched first. K double-buffered in registers (trip 1);
// trip 2 issues K+V loads at iteration top so latency hides under QK/exp/LDS.
__global__ __launch_bounds__(256) void attn_kernel(
    const unsigned short* __restrict__ qb,   // [B,H,S,64]
    const unsigned short* __restrict__ kb,   // [B,H,S,64]
    const unsigned short* __restrict__ vtb,  // [B,H,64,S]
    float* __restrict__ out_,                // [B,S,1024]
    float* __restrict__ attn) {              // [B,H,S,S]
    const int qt = 31 - (int)blockIdx.x;     // heavy blocks launch first
    const int h = blockIdx.y;
    const int b = blockIdx.z;
    const int bh = b * 16 + h;
    const int tid = threadIdx.x;
    const int w = tid >> 6;
    const int lane = tid & 63;
    const int quad = lane >> 4;
    const int cl = lane & 15;
    const int q0 = qt * 64;
    const int row0 = q0 + w * 16;
    const int jtmax = qt;                    // same for all waves of the block

    const unsigned short* Qh = qb + (size_t)bh * 2048 * 64;
    const unsigned short* Kh = kb + (size_t)bh * 2048 * 64;
    const unsigned short* Vh = vtb + (size_t)bh * 64 * 2048;
    float* attnh = attn + (size_t)bh * 2048 * 2048;

    // Q fragments (A-operand): lane holds Q[row0+cl][kc*32 + quad*8 + j]
    short8 aq0 = *(const short8*)(Qh + (size_t)(row0 + cl) * 64 + quad * 8);
    short8 aq1 = *(const short8*)(Qh + (size_t)(row0 + cl) * 64 + 32 + quad * 8);

    const float mh = exp2f(-0.5f * (float)(h + 1));  // ALiBi slope 2^-((h+1)/2)
    const float sc1 = 1.0f / 32.0f;                  // 1/sqrt(1024)

    auto loadK = [&](int jt, short8 (&kf)[8]) {
#pragma unroll
        for (int nt = 0; nt < 4; ++nt) {
            const unsigned short* Kp = Kh + (size_t)(jt * 64 + nt * 16 + cl) * 64 + quad * 8;
            kf[nt * 2] = *(const short8*)(Kp);
            kf[nt * 2 + 1] = *(const short8*)(Kp + 32);
        }
    };

    // ---- trip 1: row sums of exp(score) (max-free: |score| is O(1))
    float rsum[4] = {0.f, 0.f, 0.f, 0.f};
    auto tile1 = [&](int jt, const short8 (&kf)[8]) {
        const int j0 = jt * 64;
#pragma unroll
        for (int nt = 0; nt < 4; ++nt) {
            f32x4 s = {0.f, 0.f, 0.f, 0.f};
            s = __builtin_amdgcn_mfma_f32_16x16x32_bf16(aq0, kf[nt * 2], s, 0, 0, 0);
            s = __builtin_amdgcn_mfma_f32_16x16x32_bf16(aq1, kf[nt * 2 + 1], s, 0, 0, 0);
            const int jc = j0 + nt * 16 + cl;
#pragma unroll
            for (int rg = 0; rg < 4; ++rg) {
                int irow = row0 + quad * 4 + rg;
                if (jc <= irow)
                    rsum[rg] += __expf(s[rg] * sc1 + mh * (float)(jc - irow));
            }
        }
    };

    {
        short8 kf0[8], kf1[8];
        loadK(0, kf0);
        int jt = 0;
        for (;;) {
            if (jt < jtmax) loadK(jt + 1, kf1);
            tile1(jt, kf0);
            if (++jt > jtmax) break;
            if (jt < jtmax) loadK(jt + 1, kf0);
            tile1(jt, kf1);
            if (++jt > jtmax) break;
        }
    }
#pragma unroll
    for (int rg = 0; rg < 4; ++rg) {
        float v = rsum[rg];
        v += __shfl_xor(v, 1);
        v += __shfl_xor(v, 2);
        v += __shfl_xor(v, 4);
        v += __shfl_xor(v, 8);
        rsum[rg] = 1.0f / v;   // inv row-sum, valid on every lane of the quad
    }

    // ---- trip 2: recompute, normalize, emit attn, accumulate O = P @ V
    __shared__ unsigned short Ps[4][16][72];  // per-wave P strip, C-layout -> A-layout
    f32x4 oacc[4] = {};
    for (int jt = 0; jt <= jtmax; ++jt) {
        const int j0 = jt * 64;
        short8 kf[8], vf[8];
        loadK(jt, kf);
#pragma unroll
        for (int on = 0; on < 4; ++on) {
            const unsigned short* Vp = Vh + (size_t)(on * 16 + cl) * 2048 + j0 + quad * 8;
            vf[on * 2] = *(const short8*)(Vp);
            vf[on * 2 + 1] = *(const short8*)(Vp + 32);
        }
#pragma unroll
        for (int nt = 0; nt < 4; ++nt) {
            f32x4 s = {0.f, 0.f, 0.f, 0.f};
            s = __builtin_amdgcn_mfma_f32_16x16x32_bf16(aq0, kf[nt * 2], s, 0, 0, 0);
            s = __builtin_amdgcn_mfma_f32_16x16x32_bf16(aq1, kf[nt * 2 + 1], s, 0, 0, 0);
            const int jc = j0 + nt * 16 + cl;
#pragma unroll
            for (int rg = 0; rg < 4; ++rg) {
                int irow = row0 + quad * 4 + rg;
                float p = (jc <= irow)
                              ? __expf(s[rg] * sc1 + mh * (float)(jc - irow)) * rsum[rg]
                              : 0.f;
                Ps[w][quad * 4 + rg][nt * 16 + cl] = f2bf(p);
            }
        }
        // P strip: A-operand fragments (lane = row cl, k contiguous)
        short8 pa0 = *(const short8*)&Ps[w][cl][quad * 8];
        short8 pa1 = *(const short8*)&Ps[w][cl][32 + quad * 8];

        // attn write: row row0+cl, cols j0+quad*8..+8 and j0+32+quad*8..+8
        {
            float* arow = attnh + (size_t)(row0 + cl) * 2048 + j0;
            f32x4 v0, v1, v2, v3;
#pragma unroll
            for (int j = 0; j < 4; ++j) {
                v0[j] = bf2f((unsigned short)pa0[j]);
                v1[j] = bf2f((unsigned short)pa0[j + 4]);
                v2[j] = bf2f((unsigned short)pa1[j]);
                v3[j] = bf2f((unsigned short)pa1[j + 4]);
            }
            __builtin_nontemporal_store(v0, (f32x4*)(arow + quad * 8));
            __builtin_nontemporal_store(v1, (f32x4*)(arow + quad * 8 + 4));
            __builtin_nontemporal_store(v2, (f32x4*)(arow + 32 + quad * 8));
            __builtin_nontemporal_store(v3, (f32x4*)(arow + 32 + quad * 8 + 4));
        }

        // O += P @ V   (B-operand: vT[n][k] contiguous in k; vf issued at top)
#pragma unroll
        for (int on = 0; on < 4; ++on) {
            oacc[on] = __builtin_amdgcn_mfma_f32_16x16x32_bf16(pa0, vf[on * 2], oacc[on], 0, 0, 0);
            oacc[on] = __builtin_amdgcn_mfma_f32_16x16x32_bf16(pa1, vf[on * 2 + 1], oacc[on], 0, 0, 0);
        }
    }

    // O epilogue: out[b, s, h*64 + d]
#pragma unroll
    for (int on = 0; on < 4; ++on) {
#pragma unroll
        for (int rg = 0; rg < 4; ++rg) {
            int srow = row0 + quad * 4 + rg;
            out_[((size_t)b * 2048 + srow) * 1024 + h * 64 + on * 16 + cl] = oacc[on][rg];
        }
    }

    // zero-fill strictly-future columns (d_out is poisoned, zeros must be written)
    const int jz = (qt + 1) * 64;
    if (jz < 2048) {
        f32x4 z = {0.f, 0.f, 0.f, 0.f};
        for (int rr = 0; rr < 16; ++rr) {
            float* dst = attnh + (size_t)(q0 + w * 16 + rr) * 2048;
            for (int c = jz + lane * 4; c < 2048; c += 256)
                __builtin_nontemporal_store(z, (f32x4*)(dst + c));
        }
    }
}

// ---------------------------------------------------------------- launch
extern "C" void kernel_launch(void* const* d_in, const int* in_sizes, int n_in,
                              void* d_out, int out_size, void* d_ws, size_t ws_size,
                              hipStream_t stream) {
    const float* x = (const float*)d_in[0];     // [2,2048,1024]
    const float* Wk = (const float*)d_in[1];    // [1024,3072]
    float* out = (float*)d_out;                 // [2,2048,1024] fp32
    float* attn = out + (size_t)2 * 2048 * 1024;  // [2,16,2048,2048] fp32

    unsigned short* xb = (unsigned short*)d_ws;                 // 8 MB
    unsigned short* wtb = xb + (size_t)4096 * 1024;             // 6 MB
    unsigned short* qb = wtb + (size_t)3072 * 1024;             // 8 MB
    unsigned short* kb = qb + (size_t)32 * 2048 * 64;           // 8 MB
    unsigned short* vtb = kb + (size_t)32 * 2048 * 64;          // 8 MB

    cvt_x_kernel<<<dim3(4096), dim3(256), 0, stream>>>(x, xb, 4096 * 1024 / 4);
    cvt_wt_kernel<<<dim3(48, 16), dim3(256), 0, stream>>>(Wk, wtb);
    gemm_kqv_kernel<<<dim3(24, 32), dim3(256), 0, stream>>>(xb, wtb, qb, kb, vtb);
    attn_kernel<<<dim3(32, 16, 2), dim3(256), 0, stream>>>(qb, kb, vtb, out, attn);
}